// Round 3
// baseline (480.401 us; speedup 1.0000x reference)
//
#include <hip/hip_runtime.h>

// Problem constants: H=8, B=16, G=512, NQ=512, D=512, KD=VD=64, E=512, NORM=0.125
using u8 = unsigned char;
using u16 = unsigned short;
using u32 = unsigned int;
using u64 = unsigned long long;

typedef __attribute__((ext_vector_type(8))) __bf16 bf16x8;
typedef __attribute__((ext_vector_type(2))) __bf16 bf16x2;
typedef __attribute__((ext_vector_type(8))) u16 u16x8;
typedef __attribute__((ext_vector_type(4))) float f32x4;
typedef __attribute__((ext_vector_type(2))) float f32x2;
typedef __attribute__((ext_vector_type(2))) u32 u32x2;

#define MFMA16(A, B, C) __builtin_amdgcn_mfma_f32_16x16x32_bf16((A), (B), (C), 0, 0, 0)

#if __has_builtin(__builtin_amdgcn_exp2f)
#define EXP2(x) __builtin_amdgcn_exp2f(x)
#else
#define EXP2(x) __expf((x)*0.69314718055994531f)
#endif

__device__ __forceinline__ u16 f2bf(float f) {
  u32 u = __builtin_bit_cast(u32, f);
  u += 0x7fffu + ((u >> 16) & 1u);   // round-to-nearest-even
  return (u16)(u >> 16);
}

// async 16B/lane global->LDS DMA. lds dest must be wave-uniform base; lane i
// lands at base + i*16.
__device__ __forceinline__ void gl_lds16(const void* g, void* l) {
  __builtin_amdgcn_global_load_lds(
      (const __attribute__((address_space(1))) void*)g,
      (__attribute__((address_space(3))) void*)l, 16, 0, 0);
}

// ---------------------------------------------------------------- prep kernels

__global__ void prep_q_k(const float* __restrict__ q, u16* __restrict__ qb) {
  int idx = blockIdx.x * 256 + threadIdx.x;          // one per 8 elems
  const float4* p = (const float4*)q + (size_t)idx * 2;
  float4 a = p[0], b = p[1];
  u32 w0 = f2bf(a.x) | ((u32)f2bf(a.y) << 16);
  u32 w1 = f2bf(a.z) | ((u32)f2bf(a.w) << 16);
  u32 w2 = f2bf(b.x) | ((u32)f2bf(b.y) << 16);
  u32 w3 = f2bf(b.z) | ((u32)f2bf(b.w) << 16);
  ((uint4*)qb)[idx] = make_uint4(w0, w1, w2, w3);
}

struct WPtrs { const float* w[12]; };

// Wbt[col][d] = W_iw[h][d][kk],  col = iw*512 + h*64 + kk  (K-major for B-fragments)
// Q-branch weights (iw%3==0) pre-scaled by 0.125*log2(e) so attn uses bare exp2.
__global__ void prep_w_k(WPtrs wp, u16* __restrict__ Wbt) {
  int iw = blockIdx.x >> 3;
  int h  = blockIdx.x & 7;
  int kk = threadIdx.x & 63;
  int dd = threadIdx.x >> 6;
  float scale = ((iw % 3) == 0) ? 0.18033688011112042f : 1.0f;  // 0.125*log2e
  const float* W = wp.w[iw];
  for (int d = dd; d < 512; d += 4) {
    float v = W[((size_t)(h * 512 + d)) * 64 + kk] * scale;   // coalesced over kk
    Wbt[((size_t)(iw * 512 + h * 64 + kk)) * 512 + d] = f2bf(v);
  }
}

// Wot[h][e][v] = W_out[h][v][e]
__global__ void prep_wout_k(const float* __restrict__ wout, u16* __restrict__ Wot) {
  int h = blockIdx.x;
  int t = threadIdx.x;
  for (int ee = 0; ee < 2; ee++) {
    int e = ee * 256 + t;
    for (int v = 0; v < 64; v++)
      Wot[((size_t)(h * 512 + e)) * 64 + v] = f2bf(wout[((size_t)(h * 64 + v)) * 512 + e]);
  }
}

// ---------------------------------------------------------------- mask bit-pack
// RB[b][c][q][gc] (u64): bit (g&63) of chunk gc = mask_c(b, q, gc*64+g)
//   c0 = sd[b][q][g], c1 = att[b][g][q], c2 = att_flat[b][q][g], c3 = grp[b][q][g]

__global__ void pack_rows_k(const int* __restrict__ att, const int* __restrict__ grp,
                            const int* __restrict__ sd, u64* __restrict__ RB) {
  int t = threadIdx.x, wave = t >> 6, lane = t & 63;
  int b = blockIdx.x >> 5, qc = blockIdx.x & 31;   // 512 blocks
  int q0 = qc * 16 + wave * 4;
#pragma unroll
  for (int r = 0; r < 4; r++) {
    int q = q0 + r;
    size_t rbase = ((size_t)(b * 512 + q)) * 512;
#pragma unroll
    for (int gc = 0; gc < 8; gc++) {
      u64 m0 = __ballot(sd [rbase + gc * 64 + lane] != 0);
      u64 m2 = __ballot(att[rbase + gc * 64 + lane] != 0);
      u64 m3 = __ballot(grp[rbase + gc * 64 + lane] != 0);
      if (lane == 0) {
        size_t ob = ((size_t)(b * 4) * 512 + q) * 8 + gc;
        RB[ob]            = m0;   // c0
        RB[ob + 2 * 4096] = m2;   // c2
        RB[ob + 3 * 4096] = m3;   // c3
      }
    }
  }
}

__global__ void pack_cols_k(const int* __restrict__ att, u64* __restrict__ RB) {
  int t = threadIdx.x, wave = t >> 6, lane = t & 63;
  int b = blockIdx.x >> 3, gc = blockIdx.x & 7;    // 128 blocks
  const int* col = att + ((size_t)(b * 512 + gc * 64 + lane)) * 512;  // att[b][g][.]
#pragma unroll 4
  for (int qi = 0; qi < 128; qi++) {
    int q = wave * 128 + qi;
    u64 m = __ballot(col[q] != 0);
    if (lane == 0) RB[((size_t)(b * 4 + 1) * 512 + q) * 8 + gc] = m;
  }
}

// ---------------------------------------------------------------- pass A: all 12 projections
// C(8192 x 6144) = qb(8192 x 512) * W(512 x 6144). 128x128 tile, BK=64, 4 waves.
__global__ __launch_bounds__(256) void gemm_proj_k(const u16* __restrict__ qb,
                                                   const u16* __restrict__ Wbt,
                                                   u16* __restrict__ P) {
  __shared__ __align__(16) u16 smem[17408];  // As 8192 | Bs 8192; Cs overlays 128x136
  u16* As = smem;
  u16* Bs = smem + 8192;
  int t = threadIdx.x;
  int wave = t >> 6, lane = t & 63, quad = lane >> 4, l16 = lane & 15;
  int m0w = (wave >> 1) * 64, n0w = (wave & 1) * 64;
  int bm = blockIdx.x, bn = blockIdx.y;
  f32x4 acc[4][4] = {};
  int lr8 = lane >> 3;                 // 0..7
  int lc8 = (lane & 7) ^ lr8;         // swizzled logical chunk to fetch
  const u16* ag = qb  + ((size_t)(bm * 128 + wave * 32 + lr8)) * 512 + lc8 * 8;
  const u16* bg = Wbt + ((size_t)(bn * 128 + wave * 32 + lr8)) * 512 + lc8 * 8;
  u16* Asd = As + wave * 2048;        // wave*4 issues * 512 u16
  u16* Bsd = Bs + wave * 2048;
  for (int k0 = 0; k0 < 512; k0 += 64) {
    __syncthreads();                  // prev tile's LDS reads done
#pragma unroll
    for (int j = 0; j < 4; j++) {
      gl_lds16(ag + (size_t)j * 8 * 512 + k0, Asd + j * 512);
      gl_lds16(bg + (size_t)j * 8 * 512 + k0, Bsd + j * 512);
    }
    __syncthreads();                  // vmcnt(0) drain: tiles resident
#pragma unroll
    for (int kc = 0; kc < 2; kc++) {
      bf16x8 am[4], bnf[4];
#pragma unroll
      for (int i = 0; i < 4; i++) {
        int ca = ((kc * 4 + quad) ^ (l16 & 7)) * 8;
        am[i]  = *(const bf16x8*)&As[(m0w + i * 16 + l16) * 64 + ca];
        bnf[i] = *(const bf16x8*)&Bs[(n0w + i * 16 + l16) * 64 + ca];
      }
#pragma unroll
      for (int mt = 0; mt < 4; mt++)
#pragma unroll
        for (int nt = 0; nt < 4; nt++)
          acc[mt][nt] = MFMA16(am[mt], bnf[nt], acc[mt][nt]);
    }
  }
  // ---------------- epilogue: LDS-staged coalesced stores ----------------
  int iw = bn >> 2;                  // both 64-col groups share iw
  bool isV = (iw % 3) == 2;
  int b  = bm >> 2;
  int n0 = (bm & 3) * 128;
  u16 (*Cs)[136] = (u16(*)[136])smem;  // 128 x 136 u16 = 34816 B
  __syncthreads();
#pragma unroll
  for (int mt = 0; mt < 4; mt++)
#pragma unroll
    for (int nt = 0; nt < 4; nt++)
#pragma unroll
      for (int r = 0; r < 4; r++) {
        int rm = m0w + mt * 16 + quad * 4 + r;
        int cn = n0w + nt * 16 + l16;
        u16 v = f2bf(acc[mt][nt][r]);
        if (!isV) Cs[rm][cn] = v;
        else      Cs[cn][rm] = v;
      }
  __syncthreads();
#pragma unroll
  for (int p = 0; p < 8; p++) {
    int idx = p * 256 + t;
    int seg  = idx & 15;
    int crow = idx >> 4;
    uint4 v = *(const uint4*)&Cs[crow][seg * 8];
    if (!isV) {
      int col = seg * 8;
      int cg = col >> 6, k = col & 63;
      int h = (bn * 2 + cg) & 7;
      u16* dst = P + ((size_t)((iw * 8 + h) * 16 + b)) * 32768 + (size_t)(n0 + crow) * 64 + k;
      *(uint4*)dst = v;
    } else {
      int cg = crow >> 6, k = crow & 63;
      int h = (bn * 2 + cg) & 7;
      u16* dst = P + ((size_t)((iw * 8 + h) * 16 + b)) * 32768 + (size_t)k * 512 + n0 + seg * 8;
      *(uint4*)dst = v;
    }
  }
}

// ---------------------------------------------------------------- pass B: fused masked attention
// 1-D grid, 1024 blocks; block 256 = 4 waves, each wave owns 16 q-rows.
// XCD swizzle keeps each (b,h)'s 512KB K/V panel on one XCD's L2 (FETCH 281->51MB).
// T14 reg-staging: next tile's K/V loaded to REGISTERS at top of compute (latency
// hidden under MFMA+softmax), ds_write'd to LDS after the post-compute barrier —
// exposed per-gt latency is now only the ds_write drain. Swapped QK^T (mfma(K,Q))
// makes each lane's 16 scores belong to one q-row with 4 consecutive g per nt:
// masked-exp packs via cvt_pk into b64 writes (4/gt vs 16 b16), mask bits fold
// into the packed words. Raw v_exp_f32 (weights pre-scaled by 0.125*log2e).
__global__ __launch_bounds__(256, 4) void attn_k(const u16* __restrict__ P,
                                                 const u64* __restrict__ RB,
                                                 u16* __restrict__ heads) {
  __shared__ __align__(16) u16 QPs[4096];    // [64][64]: Q at class start, then P scratch
  __shared__ __align__(16) u16 Ks[4096];     // [64][64] chunk-swizzled
  __shared__ __align__(16) u16 Vs[4096];     // [v][g] chunk-swizzled
  __shared__ __align__(16) u64 Ms[64][10];   // row bitmasks, padded (conflict-free b64)
  int t = threadIdx.x;
  int wave = t >> 6, lane = t & 63, quad = lane >> 4, l16 = lane & 15;
  // id = 8*((bh>>3)*8 + qt) + (bh&7)  — bijective; id%8 keyed to bh
  int id = blockIdx.x;
  int r8 = id & 7, kk2 = id >> 3;
  int bh = ((kk2 >> 3) << 3) | r8;
  int qt = kk2 & 7;
  int b = bh & 15, h = bh >> 4;
  int q0 = qt * 64;
  int lr8 = lane >> 3, lc8 = (lane & 7) ^ lr8;
  f32x4 O[4] = {};
  f32x4 Oden = {};
  u16x8 ov = {0x3F80, 0x3F80, 0x3F80, 0x3F80, 0x3F80, 0x3F80, 0x3F80, 0x3F80};
  bf16x8 ones = __builtin_bit_cast(bf16x8, ov);   // bf16 1.0 x8

  uint4 rK[2], rV[2], rQ[2], rM;
  char* KsB = (char*)Ks;
  char* VsB = (char*)Vs;
  char* QsB = (char*)QPs;
  int stOff = (wave * 16 + lr8) * 128 + (lane & 7) * 16;   // j=1 adds 1024

  auto loadKV = [&](int c, int g0) {
    const u16* PK = P + ((size_t)((3 * c + 1) * 8 + h) * 16 + b) * 32768;
    const u16* PV = P + ((size_t)((3 * c + 2) * 8 + h) * 16 + b) * 32768;
    rK[0] = *(const uint4*)(PK + (size_t)(g0 + wave * 16 + lr8) * 64 + lc8 * 8);
    rK[1] = *(const uint4*)(PK + (size_t)(g0 + wave * 16 + 8 + lr8) * 64 + lc8 * 8);
    rV[0] = *(const uint4*)(PV + (size_t)(wave * 16 + lr8) * 512 + g0 + lc8 * 8);
    rV[1] = *(const uint4*)(PV + (size_t)(wave * 16 + 8 + lr8) * 512 + g0 + lc8 * 8);
  };
  auto storeKV = [&]() {
    *(uint4*)(KsB + stOff)        = rK[0];
    *(uint4*)(KsB + stOff + 1024) = rK[1];
    *(uint4*)(VsB + stOff)        = rV[0];
    *(uint4*)(VsB + stOff + 1024) = rV[1];
  };
  auto loadQM = [&](int c) {
    const u16* PQ = P + ((size_t)((3 * c) * 8 + h) * 16 + b) * 32768;
    rQ[0] = *(const uint4*)(PQ + (size_t)(q0 + wave * 16 + lr8) * 64 + lc8 * 8);
    rQ[1] = *(const uint4*)(PQ + (size_t)(q0 + wave * 16 + 8 + lr8) * 64 + lc8 * 8);
    rM    = *(const uint4*)(RB + ((size_t)((b * 4 + c) * 512 + q0 + (t >> 2))) * 8 + (t & 3) * 2);
  };
  auto storeQM = [&]() {
    *(uint4*)(QsB + stOff)        = rQ[0];
    *(uint4*)(QsB + stOff + 1024) = rQ[1];
    *(uint4*)((char*)Ms + (t >> 2) * 80 + (t & 3) * 16) = rM;
  };

  // prologue: tile (c=0, gt=0)
  loadKV(0, 0);
  loadQM(0);
  storeKV();
  storeQM();
  __syncthreads();

  bf16x8 aq0, aq1;
  for (int tt = 0; tt < 32; tt++) {
    int gt = tt & 7;
    if (gt == 0) {                 // Q fragments gt-invariant: hoist (QPs then free for P)
      aq0 = *(const bf16x8*)&QPs[(wave * 16 + l16) * 64 + ((quad) ^ (l16 & 7)) * 8];
      aq1 = *(const bf16x8*)&QPs[(wave * 16 + l16) * 64 + ((4 + quad) ^ (l16 & 7)) * 8];
    }
    int nxt = tt + 1;
    bool haveNext = (nxt < 32);
    int nc = nxt >> 3, ngt = nxt & 7;
    if (haveNext) {
      loadKV(nc, ngt * 64);        // issue now; lands during compute below
      if (ngt == 0) loadQM(nc);
    }
    // --- QK^T, swapped operands: D rows = g (A=K), cols = q (B=Q) ---
    f32x4 S[4];
#pragma unroll
    for (int nt = 0; nt < 4; nt++) {
      bf16x8 bk0 = *(const bf16x8*)&Ks[(nt * 16 + l16) * 64 + ((quad) ^ (l16 & 7)) * 8];
      bf16x8 bk1 = *(const bf16x8*)&Ks[(nt * 16 + l16) * 64 + ((4 + quad) ^ (l16 & 7)) * 8];
      f32x4 sa = {};
      sa = MFMA16(bk0, aq0, sa);
      sa = MFMA16(bk1, aq1, sa);
      S[nt] = sa;                  // S[nt][r]: q = wave*16+l16, g = gt*64+nt*16+quad*4+r
    }
    // --- masked exp -> packed bf16, b64 writes into Ps (overlays QPs) ---
    {
      u64 m = Ms[wave * 16 + l16][gt];
      u32 mlo = (u32)m, mhi = (u32)(m >> 32);
      int shq = quad * 4;
      u32 tb0 = mlo >> shq, tb1 = mlo >> (shq + 16);
      u32 tb2 = mhi >> shq, tb3 = mhi >> (shq + 16);
      u32 tbs[4] = {tb0, tb1, tb2, tb3};
      char* PsB = (char*)QPs + (wave * 16 + l16) * 128 + (quad & 1) * 8;
#pragma unroll
      for (int nt = 0; nt < 4; nt++) {
        u32 tn = tbs[nt];
        f32x2 p0 = {EXP2(S[nt][0]), EXP2(S[nt][1])};
        f32x2 p1 = {EXP2(S[nt][2]), EXP2(S[nt][3])};
        u32 w0 = __builtin_bit_cast(u32, __builtin_convertvector(p0, bf16x2));
        u32 w1 = __builtin_bit_cast(u32, __builtin_convertvector(p1, bf16x2));
        u32 ma = (u32)((int)(tn << 31) >> 31);   // bit0 -> full mask (v_bfe_i32)
        u32 mb = (u32)((int)(tn << 30) >> 31);
        u32 mc = (u32)((int)(tn << 29) >> 31);
        u32 md = (u32)((int)(tn << 28) >> 31);
        w0 &= (ma & 0x0000ffffu) | (mb & 0xffff0000u);
        w1 &= (mc & 0x0000ffffu) | (md & 0xffff0000u);
        u32x2 wp = {w0, w1};
        int ch = (nt * 2 + (quad >> 1)) ^ (l16 & 7);
        *(u32x2*)(PsB + ch * 16) = wp;
      }
    }
    // --- PV + denominator (P rows are wave-private: no barrier needed) ---
#pragma unroll
    for (int kc = 0; kc < 2; kc++) {
      bf16x8 ap = *(const bf16x8*)&QPs[(wave * 16 + l16) * 64 + (((kc * 4 + quad) ^ (l16 & 7)) * 8)];
#pragma unroll
      for (int vt = 0; vt < 4; vt++) {
        bf16x8 bv = *(const bf16x8*)&Vs[(vt * 16 + l16) * 64 + (((kc * 4 + quad) ^ (l16 & 7)) * 8)];
        O[vt] = MFMA16(ap, bv, O[vt]);
      }
      Oden = MFMA16(ap, ones, Oden);             // row-sum of P = denominator
    }
    __syncthreads();               // all LDS reads of this gt done
    if (haveNext) {
      storeKV();                   // vmcnt wait here: loads flew during compute
      if (ngt == 0) storeQM();
    }
    __syncthreads();               // stores visible for next gt
  }
#pragma unroll
  for (int r = 0; r < 4; r++) {
    float den = Oden[r];           // every lane holds its rows' denominator
#pragma unroll
    for (int vt = 0; vt < 4; vt++) {
      float val = (den > 0.f) ? O[vt][r] / den : 0.f;
      heads[((size_t)(h * 16 + b) * 512 + q0 + wave * 16 + quad * 4 + r) * 64 + vt * 16 + l16] =
          f2bf(val);
    }
  }
}

// ---------------------------------------------------------------- pass C: out = heads x W_out
// out(8192 x 512) = heads[(b,q),(h,v)=512] * Wot. 64x64 tile, K-loop over h.
__global__ __launch_bounds__(256) void gemm_out_k(const u16* __restrict__ heads,
                                                  const u16* __restrict__ Wot,
                                                  float* __restrict__ out) {
  __shared__ __align__(16) u16 As[4096];
  __shared__ __align__(16) u16 Bs[4096];
  int t = threadIdx.x;
  int wave = t >> 6, lane = t & 63, quad = lane >> 4, l16 = lane & 15;
  int m0 = blockIdx.x * 64, e0 = blockIdx.y * 64;
  int b = m0 >> 9, q0 = m0 & 511;
  int lr8 = lane >> 3, lc8 = (lane & 7) ^ lr8;
  f32x4 acc[4] = {};
  for (int h = 0; h < 8; h++) {
    __syncthreads();
#pragma unroll
    for (int j = 0; j < 2; j++) {
      gl_lds16(heads + ((size_t)(h * 16 + b) * 512 + q0 + wave * 16 + j * 8 + lr8) * 64 + lc8 * 8,
               As + wave * 1024 + j * 512);
      gl_lds16(Wot + ((size_t)(h * 512 + e0 + wave * 16 + j * 8 + lr8)) * 64 + lc8 * 8,
               Bs + wave * 1024 + j * 512);
    }
    __syncthreads();
#pragma unroll
    for (int kc = 0; kc < 2; kc++) {
      bf16x8 af = *(const bf16x8*)&As[(wave * 16 + l16) * 64 + ((kc * 4 + quad) ^ (l16 & 7)) * 8];
#pragma unroll
      for (int nt = 0; nt < 4; nt++) {
        bf16x8 bfr = *(const bf16x8*)&Bs[(nt * 16 + l16) * 64 + ((kc * 4 + quad) ^ (l16 & 7)) * 8];
        acc[nt] = MFMA16(af, bfr, acc[nt]);
      }
    }
  }
#pragma unroll
  for (int nt = 0; nt < 4; nt++)
#pragma unroll
    for (int r = 0; r < 4; r++)
      out[((size_t)(b * 512 + q0 + wave * 16 + quad * 4 + r)) * 512 + e0 + nt * 16 + l16] = acc[nt][r];
}

// ---------------------------------------------------------------- launch

extern "C" void kernel_launch(void* const* d_in, const int* in_sizes, int n_in,
                              void* d_out, int out_size, void* d_ws, size_t ws_size,
                              hipStream_t stream) {
  const float* q   = (const float*)d_in[0];
  const int*   att = (const int*)d_in[1];
  const int*   grp = (const int*)d_in[2];
  const int*   sd  = (const int*)d_in[3];
  WPtrs wp;
  for (int j = 0; j < 12; j++) wp.w[j] = (const float*)d_in[4 + j];
  const float* wout = (const float*)d_in[16];

  char* ws = (char*)d_ws;
  // workspace layout (total 126,353,408 B)
  u16* qb    = (u16*)(ws + 0);            //   8,388,608
  u16* Wbt   = (u16*)(ws + 8388608);      //   6,291,456
  u16* Wot   = (u16*)(ws + 14680064);     //     524,288
  u64* RB    = (u64*)(ws + 15204352);     //   2,097,152  (bit-packed masks)
  u16* P     = (u16*)(ws + 17301504);     // 100,663,296
  u16* heads = (u16*)(ws + 117964800);    //   8,388,608
  float* out = (float*)d_out;

  pack_rows_k<<<512, 256, 0, stream>>>(att, grp, sd, RB);
  pack_cols_k<<<128, 256, 0, stream>>>(att, RB);
  prep_q_k<<<2048, 256, 0, stream>>>(q, qb);
  prep_w_k<<<96, 256, 0, stream>>>(wp, Wbt);
  prep_wout_k<<<8, 256, 0, stream>>>(wout, Wot);
  gemm_proj_k<<<dim3(64, 48), 256, 0, stream>>>(qb, Wbt, P);
  attn_k<<<1024, 256, 0, stream>>>(P, RB, heads);
  gemm_out_k<<<dim3(128, 8), 256, 0, stream>>>(heads, Wot, out);
}

// Round 4
// 384.520 us; speedup vs baseline: 1.2494x; 1.2494x over previous
//
#include <hip/hip_runtime.h>

// Problem constants: H=8, B=16, G=512, NQ=512, D=512, KD=VD=64, E=512, NORM=0.125
using u8 = unsigned char;
using u16 = unsigned short;
using u32 = unsigned int;
using u64 = unsigned long long;

typedef __attribute__((ext_vector_type(8))) __bf16 bf16x8;
typedef __attribute__((ext_vector_type(2))) __bf16 bf16x2;
typedef __attribute__((ext_vector_type(8))) u16 u16x8;
typedef __attribute__((ext_vector_type(4))) float f32x4;
typedef __attribute__((ext_vector_type(2))) float f32x2;
typedef __attribute__((ext_vector_type(2))) u32 u32x2;

#define MFMA16(A, B, C) __builtin_amdgcn_mfma_f32_16x16x32_bf16((A), (B), (C), 0, 0, 0)

#if __has_builtin(__builtin_amdgcn_exp2f)
#define EXP2(x) __builtin_amdgcn_exp2f(x)
#else
#define EXP2(x) __expf((x)*0.69314718055994531f)
#endif

__device__ __forceinline__ u16 f2bf(float f) {
  u32 u = __builtin_bit_cast(u32, f);
  u += 0x7fffu + ((u >> 16) & 1u);   // round-to-nearest-even
  return (u16)(u >> 16);
}

// async 16B/lane global->LDS DMA. lds dest must be wave-uniform base; lane i
// lands at base + i*16.
__device__ __forceinline__ void gl_lds16(const void* g, void* l) {
  __builtin_amdgcn_global_load_lds(
      (const __attribute__((address_space(1))) void*)g,
      (__attribute__((address_space(3))) void*)l, 16, 0, 0);
}

// ---------------------------------------------------------------- prep kernels

__global__ void prep_q_k(const float* __restrict__ q, u16* __restrict__ qb) {
  int idx = blockIdx.x * 256 + threadIdx.x;          // one per 8 elems
  const float4* p = (const float4*)q + (size_t)idx * 2;
  float4 a = p[0], b = p[1];
  u32 w0 = f2bf(a.x) | ((u32)f2bf(a.y) << 16);
  u32 w1 = f2bf(a.z) | ((u32)f2bf(a.w) << 16);
  u32 w2 = f2bf(b.x) | ((u32)f2bf(b.y) << 16);
  u32 w3 = f2bf(b.z) | ((u32)f2bf(b.w) << 16);
  ((uint4*)qb)[idx] = make_uint4(w0, w1, w2, w3);
}

struct WPtrs { const float* w[12]; };

// Wbt[col][d] = W_iw[h][d][kk],  col = iw*512 + h*64 + kk  (K-major for B-fragments)
// Q-branch weights (iw%3==0) pre-scaled by 0.125*log2(e) so attn uses bare exp2.
__global__ void prep_w_k(WPtrs wp, u16* __restrict__ Wbt) {
  int iw = blockIdx.x >> 3;
  int h  = blockIdx.x & 7;
  int kk = threadIdx.x & 63;
  int dd = threadIdx.x >> 6;
  float scale = ((iw % 3) == 0) ? 0.18033688011112042f : 1.0f;  // 0.125*log2e
  const float* W = wp.w[iw];
  for (int d = dd; d < 512; d += 4) {
    float v = W[((size_t)(h * 512 + d)) * 64 + kk] * scale;   // coalesced over kk
    Wbt[((size_t)(iw * 512 + h * 64 + kk)) * 512 + d] = f2bf(v);
  }
}

// Wot[h][e][v] = W_out[h][v][e]
__global__ void prep_wout_k(const float* __restrict__ wout, u16* __restrict__ Wot) {
  int h = blockIdx.x;
  int t = threadIdx.x;
  for (int ee = 0; ee < 2; ee++) {
    int e = ee * 256 + t;
    for (int v = 0; v < 64; v++)
      Wot[((size_t)(h * 512 + e)) * 64 + v] = f2bf(wout[((size_t)(h * 64 + v)) * 512 + e]);
  }
}

// ---------------------------------------------------------------- mask bit-pack
// RB[b][c][q][gc] (u64): bit (g&63) of chunk gc = mask_c(b, q, gc*64+g)
//   c0 = sd[b][q][g], c1 = att[b][g][q], c2 = att_flat[b][q][g], c3 = grp[b][q][g]

__global__ void pack_rows_k(const int* __restrict__ att, const int* __restrict__ grp,
                            const int* __restrict__ sd, u64* __restrict__ RB) {
  int t = threadIdx.x, wave = t >> 6, lane = t & 63;
  int b = blockIdx.x >> 5, qc = blockIdx.x & 31;   // 512 blocks
  int q0 = qc * 16 + wave * 4;
#pragma unroll
  for (int r = 0; r < 4; r++) {
    int q = q0 + r;
    size_t rbase = ((size_t)(b * 512 + q)) * 512;
#pragma unroll
    for (int gc = 0; gc < 8; gc++) {
      u64 m0 = __ballot(sd [rbase + gc * 64 + lane] != 0);
      u64 m2 = __ballot(att[rbase + gc * 64 + lane] != 0);
      u64 m3 = __ballot(grp[rbase + gc * 64 + lane] != 0);
      if (lane == 0) {
        size_t ob = ((size_t)(b * 4) * 512 + q) * 8 + gc;
        RB[ob]            = m0;   // c0
        RB[ob + 2 * 4096] = m2;   // c2
        RB[ob + 3 * 4096] = m3;   // c3
      }
    }
  }
}

__global__ void pack_cols_k(const int* __restrict__ att, u64* __restrict__ RB) {
  int t = threadIdx.x, wave = t >> 6, lane = t & 63;
  int b = blockIdx.x >> 3, gc = blockIdx.x & 7;    // 128 blocks
  const int* col = att + ((size_t)(b * 512 + gc * 64 + lane)) * 512;  // att[b][g][.]
#pragma unroll 4
  for (int qi = 0; qi < 128; qi++) {
    int q = wave * 128 + qi;
    u64 m = __ballot(col[q] != 0);
    if (lane == 0) RB[((size_t)(b * 4 + 1) * 512 + q) * 8 + gc] = m;
  }
}

// ---------------------------------------------------------------- pass A: all 12 projections
// C(8192 x 6144) = qb(8192 x 512) * W(512 x 6144). 128x128 tile, BK=64, 4 waves.
__global__ __launch_bounds__(256) void gemm_proj_k(const u16* __restrict__ qb,
                                                   const u16* __restrict__ Wbt,
                                                   u16* __restrict__ P) {
  __shared__ __align__(16) u16 smem[17408];  // As 8192 | Bs 8192; Cs overlays 128x136
  u16* As = smem;
  u16* Bs = smem + 8192;
  int t = threadIdx.x;
  int wave = t >> 6, lane = t & 63, quad = lane >> 4, l16 = lane & 15;
  int m0w = (wave >> 1) * 64, n0w = (wave & 1) * 64;
  int bm = blockIdx.x, bn = blockIdx.y;
  f32x4 acc[4][4] = {};
  int lr8 = lane >> 3;                 // 0..7
  int lc8 = (lane & 7) ^ lr8;         // swizzled logical chunk to fetch
  const u16* ag = qb  + ((size_t)(bm * 128 + wave * 32 + lr8)) * 512 + lc8 * 8;
  const u16* bg = Wbt + ((size_t)(bn * 128 + wave * 32 + lr8)) * 512 + lc8 * 8;
  u16* Asd = As + wave * 2048;        // wave*4 issues * 512 u16
  u16* Bsd = Bs + wave * 2048;
  for (int k0 = 0; k0 < 512; k0 += 64) {
    __syncthreads();                  // prev tile's LDS reads done
#pragma unroll
    for (int j = 0; j < 4; j++) {
      gl_lds16(ag + (size_t)j * 8 * 512 + k0, Asd + j * 512);
      gl_lds16(bg + (size_t)j * 8 * 512 + k0, Bsd + j * 512);
    }
    __syncthreads();                  // vmcnt(0) drain: tiles resident
#pragma unroll
    for (int kc = 0; kc < 2; kc++) {
      bf16x8 am[4], bnf[4];
#pragma unroll
      for (int i = 0; i < 4; i++) {
        int ca = ((kc * 4 + quad) ^ (l16 & 7)) * 8;
        am[i]  = *(const bf16x8*)&As[(m0w + i * 16 + l16) * 64 + ca];
        bnf[i] = *(const bf16x8*)&Bs[(n0w + i * 16 + l16) * 64 + ca];
      }
#pragma unroll
      for (int mt = 0; mt < 4; mt++)
#pragma unroll
        for (int nt = 0; nt < 4; nt++)
          acc[mt][nt] = MFMA16(am[mt], bnf[nt], acc[mt][nt]);
    }
  }
  // ---------------- epilogue: LDS-staged coalesced stores ----------------
  int iw = bn >> 2;                  // both 64-col groups share iw
  bool isV = (iw % 3) == 2;
  int b  = bm >> 2;
  int n0 = (bm & 3) * 128;
  u16 (*Cs)[136] = (u16(*)[136])smem;  // 128 x 136 u16 = 34816 B
  __syncthreads();
#pragma unroll
  for (int mt = 0; mt < 4; mt++)
#pragma unroll
    for (int nt = 0; nt < 4; nt++)
#pragma unroll
      for (int r = 0; r < 4; r++) {
        int rm = m0w + mt * 16 + quad * 4 + r;
        int cn = n0w + nt * 16 + l16;
        u16 v = f2bf(acc[mt][nt][r]);
        if (!isV) Cs[rm][cn] = v;
        else      Cs[cn][rm] = v;
      }
  __syncthreads();
#pragma unroll
  for (int p = 0; p < 8; p++) {
    int idx = p * 256 + t;
    int seg  = idx & 15;
    int crow = idx >> 4;
    uint4 v = *(const uint4*)&Cs[crow][seg * 8];
    if (!isV) {
      int col = seg * 8;
      int cg = col >> 6, k = col & 63;
      int h = (bn * 2 + cg) & 7;
      u16* dst = P + ((size_t)((iw * 8 + h) * 16 + b)) * 32768 + (size_t)(n0 + crow) * 64 + k;
      *(uint4*)dst = v;
    } else {
      int cg = crow >> 6, k = crow & 63;
      int h = (bn * 2 + cg) & 7;
      u16* dst = P + ((size_t)((iw * 8 + h) * 16 + b)) * 32768 + (size_t)k * 512 + n0 + seg * 8;
      *(uint4*)dst = v;
    }
  }
}

// ---------------------------------------------------------------- pass B: fused masked attention
// 1-D grid, 1024 blocks; block 256 = 4 waves, each wave owns 16 q-rows.
// XCD swizzle keeps each (b,h)'s 512KB K/V panel on one XCD's L2.
// T14 reg-staging with NAMED SCALARS ONLY (round 3's lambda+array version put
// the staging tiles in scratch: VGPR=48, WRITE_SIZE 376MB — rule #20). Next
// tile's K/V loaded to named uint4 regs at top of compute (latency hidden under
// MFMA+softmax), ds_write'd after the post-compute barrier. Swapped QK^T
// (mfma(K,Q)): each lane's 16 scores = one q-row, 4 consecutive g per nt;
// masked-exp packs via cvt_pk into b64 writes, mask bits fold into packed
// words. Raw v_exp_f32 (weights pre-scaled by 0.125*log2e).
__global__ __launch_bounds__(256) void attn_k(const u16* __restrict__ P,
                                              const u64* __restrict__ RB,
                                              u16* __restrict__ heads) {
  __shared__ __align__(16) u16 QPs[4096];    // [64][64]: Q at class start, then P scratch
  __shared__ __align__(16) u16 Ks[4096];     // [64][64] chunk-swizzled
  __shared__ __align__(16) u16 Vs[4096];     // [v][g] chunk-swizzled
  __shared__ __align__(16) u64 Ms[64][10];   // row bitmasks, padded (conflict-free b64)
  int t = threadIdx.x;
  int wave = t >> 6, lane = t & 63, quad = lane >> 4, l16 = lane & 15;
  // id = 8*((bh>>3)*8 + qt) + (bh&7)  — bijective; id%8 keyed to bh
  int id = blockIdx.x;
  int r8 = id & 7, kk2 = id >> 3;
  int bh = ((kk2 >> 3) << 3) | r8;
  int qt = kk2 & 7;
  int b = bh & 15, h = bh >> 4;
  int q0 = qt * 64;
  int lr8 = lane >> 3, lc8 = (lane & 7) ^ lr8;
  f32x4 O0 = {}, O1 = {}, O2 = {}, O3 = {};
  f32x4 Oden = {};
  u16x8 ov = {0x3F80, 0x3F80, 0x3F80, 0x3F80, 0x3F80, 0x3F80, 0x3F80, 0x3F80};
  bf16x8 ones = __builtin_bit_cast(bf16x8, ov);   // bf16 1.0 x8

  uint4 rK0, rK1, rV0, rV1, rQ0, rQ1, rM;
  char* KsB = (char*)Ks;
  char* VsB = (char*)Vs;
  char* QsB = (char*)QPs;
  int stOff = (wave * 16 + lr8) * 128 + (lane & 7) * 16;   // +1024 for second 8 rows

// all staging through named scalars; macros = textual inline, nothing address-taken
#define LOADKV(c, g0) {                                                              \
    const u16* PK_ = P + ((size_t)((3 * (c) + 1) * 8 + h) * 16 + b) * 32768;         \
    const u16* PV_ = P + ((size_t)((3 * (c) + 2) * 8 + h) * 16 + b) * 32768;         \
    rK0 = *(const uint4*)(PK_ + (size_t)((g0) + wave * 16 + lr8) * 64 + lc8 * 8);    \
    rK1 = *(const uint4*)(PK_ + (size_t)((g0) + wave * 16 + 8 + lr8) * 64 + lc8 * 8);\
    rV0 = *(const uint4*)(PV_ + (size_t)(wave * 16 + lr8) * 512 + (g0) + lc8 * 8);   \
    rV1 = *(const uint4*)(PV_ + (size_t)(wave * 16 + 8 + lr8) * 512 + (g0) + lc8 * 8);}
#define STOREKV() {                                                                  \
    *(uint4*)(KsB + stOff)        = rK0;                                             \
    *(uint4*)(KsB + stOff + 1024) = rK1;                                             \
    *(uint4*)(VsB + stOff)        = rV0;                                             \
    *(uint4*)(VsB + stOff + 1024) = rV1; }
#define LOADQM(c) {                                                                  \
    const u16* PQ_ = P + ((size_t)((3 * (c)) * 8 + h) * 16 + b) * 32768;             \
    rQ0 = *(const uint4*)(PQ_ + (size_t)(q0 + wave * 16 + lr8) * 64 + lc8 * 8);      \
    rQ1 = *(const uint4*)(PQ_ + (size_t)(q0 + wave * 16 + 8 + lr8) * 64 + lc8 * 8);  \
    rM  = *(const uint4*)(RB + ((size_t)((b * 4 + (c)) * 512 + q0 + (t >> 2))) * 8 + (t & 3) * 2); }
#define STOREQM() {                                                                  \
    *(uint4*)(QsB + stOff)        = rQ0;                                             \
    *(uint4*)(QsB + stOff + 1024) = rQ1;                                             \
    *(uint4*)((char*)Ms + (t >> 2) * 80 + (t & 3) * 16) = rM; }

  // prologue: tile (c=0, gt=0)
  LOADKV(0, 0);
  LOADQM(0);
  STOREKV();
  STOREQM();
  __syncthreads();

  bf16x8 aq0, aq1;
  for (int tt = 0; tt < 32; tt++) {
    int gt = tt & 7;
    if (gt == 0) {                 // Q fragments gt-invariant: hoist (QPs then free for P)
      aq0 = *(const bf16x8*)&QPs[(wave * 16 + l16) * 64 + ((quad) ^ (l16 & 7)) * 8];
      aq1 = *(const bf16x8*)&QPs[(wave * 16 + l16) * 64 + ((4 + quad) ^ (l16 & 7)) * 8];
    }
    int nxt = tt + 1;
    int nc = nxt >> 3, ngt = nxt & 7;
    if (nxt < 32) {
      LOADKV(nc, ngt * 64);        // issue now; lands during compute below
      if (ngt == 0) LOADQM(nc);
    }
    // --- QK^T, swapped operands: D rows = g (A=K), cols = q (B=Q) ---
    f32x4 S0, S1, S2, S3;
#define QKNT(Sn, nt) {                                                                \
      bf16x8 bk0_ = *(const bf16x8*)&Ks[((nt) * 16 + l16) * 64 + ((quad) ^ (l16 & 7)) * 8];     \
      bf16x8 bk1_ = *(const bf16x8*)&Ks[((nt) * 16 + l16) * 64 + ((4 + quad) ^ (l16 & 7)) * 8]; \
      f32x4 sa_ = {};                                                                 \
      sa_ = MFMA16(bk0_, aq0, sa_);                                                   \
      sa_ = MFMA16(bk1_, aq1, sa_);                                                   \
      Sn = sa_; }
    QKNT(S0, 0) QKNT(S1, 1) QKNT(S2, 2) QKNT(S3, 3)
    // S*[r]: q = wave*16+l16, g = gt*64 + nt*16 + quad*4 + r
    // --- masked exp -> packed bf16, b64 writes into Ps (overlays QPs) ---
    {
      u64 m = Ms[wave * 16 + l16][gt];
      u32 mlo = (u32)m, mhi = (u32)(m >> 32);
      int shq = quad * 4;
      u32 tb0 = mlo >> shq, tb1 = mlo >> (shq + 16);
      u32 tb2 = mhi >> shq, tb3 = mhi >> (shq + 16);
      char* PsB = (char*)QPs + (wave * 16 + l16) * 128 + (quad & 1) * 8;
#define PPACK(Sn, tn, nt) {                                                           \
        f32x2 p0_ = {EXP2(Sn[0]), EXP2(Sn[1])};                                       \
        f32x2 p1_ = {EXP2(Sn[2]), EXP2(Sn[3])};                                       \
        u32 w0_ = __builtin_bit_cast(u32, __builtin_convertvector(p0_, bf16x2));      \
        u32 w1_ = __builtin_bit_cast(u32, __builtin_convertvector(p1_, bf16x2));      \
        u32 ma_ = (u32)((int)((tn) << 31) >> 31);                                     \
        u32 mb_ = (u32)((int)((tn) << 30) >> 31);                                     \
        u32 mc_ = (u32)((int)((tn) << 29) >> 31);                                     \
        u32 md_ = (u32)((int)((tn) << 28) >> 31);                                     \
        w0_ &= (ma_ & 0x0000ffffu) | (mb_ & 0xffff0000u);                             \
        w1_ &= (mc_ & 0x0000ffffu) | (md_ & 0xffff0000u);                             \
        u32x2 wp_ = {w0_, w1_};                                                       \
        int ch_ = ((nt) * 2 + (quad >> 1)) ^ (l16 & 7);                               \
        *(u32x2*)(PsB + ch_ * 16) = wp_; }
      PPACK(S0, tb0, 0) PPACK(S1, tb1, 1) PPACK(S2, tb2, 2) PPACK(S3, tb3, 3)
    }
    // --- PV + denominator (P rows are wave-private: no barrier needed) ---
#define PVKC(kc) {                                                                    \
      bf16x8 ap_ = *(const bf16x8*)&QPs[(wave * 16 + l16) * 64 + ((((kc) * 4 + quad) ^ (l16 & 7)) * 8)]; \
      bf16x8 bv0_ = *(const bf16x8*)&Vs[(0 * 16 + l16) * 64 + ((((kc) * 4 + quad) ^ (l16 & 7)) * 8)];    \
      bf16x8 bv1_ = *(const bf16x8*)&Vs[(1 * 16 + l16) * 64 + ((((kc) * 4 + quad) ^ (l16 & 7)) * 8)];    \
      bf16x8 bv2_ = *(const bf16x8*)&Vs[(2 * 16 + l16) * 64 + ((((kc) * 4 + quad) ^ (l16 & 7)) * 8)];    \
      bf16x8 bv3_ = *(const bf16x8*)&Vs[(3 * 16 + l16) * 64 + ((((kc) * 4 + quad) ^ (l16 & 7)) * 8)];    \
      O0 = MFMA16(ap_, bv0_, O0);                                                     \
      O1 = MFMA16(ap_, bv1_, O1);                                                     \
      O2 = MFMA16(ap_, bv2_, O2);                                                     \
      O3 = MFMA16(ap_, bv3_, O3);                                                     \
      Oden = MFMA16(ap_, ones, Oden); }
    PVKC(0) PVKC(1)
    __syncthreads();               // all LDS reads of this gt done
    if (nxt < 32) {
      STOREKV();                   // vmcnt wait lands here: loads flew during compute
      if (ngt == 0) STOREQM();
    }
    __syncthreads();               // stores visible for next gt
  }
#pragma unroll
  for (int r = 0; r < 4; r++) {
    float den = Oden[r];           // every lane holds its rows' denominator
    float i0 = (den > 0.f) ? O0[r] / den : 0.f;
    float i1 = (den > 0.f) ? O1[r] / den : 0.f;
    float i2 = (den > 0.f) ? O2[r] / den : 0.f;
    float i3 = (den > 0.f) ? O3[r] / den : 0.f;
    size_t base = ((size_t)(h * 16 + b) * 512 + q0 + wave * 16 + quad * 4 + r) * 64 + l16;
    heads[base + 0]  = f2bf(i0);
    heads[base + 16] = f2bf(i1);
    heads[base + 32] = f2bf(i2);
    heads[base + 48] = f2bf(i3);
  }
}

// ---------------------------------------------------------------- pass C: out = heads x W_out
// out(8192 x 512) = heads[(b,q),(h,v)=512] * Wot. 64x64 tile, K-loop over h.
__global__ __launch_bounds__(256) void gemm_out_k(const u16* __restrict__ heads,
                                                  const u16* __restrict__ Wot,
                                                  float* __restrict__ out) {
  __shared__ __align__(16) u16 As[4096];
  __shared__ __align__(16) u16 Bs[4096];
  int t = threadIdx.x;
  int wave = t >> 6, lane = t & 63, quad = lane >> 4, l16 = lane & 15;
  int m0 = blockIdx.x * 64, e0 = blockIdx.y * 64;
  int b = m0 >> 9, q0 = m0 & 511;
  int lr8 = lane >> 3, lc8 = (lane & 7) ^ lr8;
  f32x4 acc[4] = {};
  for (int h = 0; h < 8; h++) {
    __syncthreads();
#pragma unroll
    for (int j = 0; j < 2; j++) {
      gl_lds16(heads + ((size_t)(h * 16 + b) * 512 + q0 + wave * 16 + j * 8 + lr8) * 64 + lc8 * 8,
               As + wave * 1024 + j * 512);
      gl_lds16(Wot + ((size_t)(h * 512 + e0 + wave * 16 + j * 8 + lr8)) * 64 + lc8 * 8,
               Bs + wave * 1024 + j * 512);
    }
    __syncthreads();
#pragma unroll
    for (int kc = 0; kc < 2; kc++) {
      bf16x8 af = *(const bf16x8*)&As[(wave * 16 + l16) * 64 + ((kc * 4 + quad) ^ (l16 & 7)) * 8];
#pragma unroll
      for (int nt = 0; nt < 4; nt++) {
        bf16x8 bfr = *(const bf16x8*)&Bs[(nt * 16 + l16) * 64 + ((kc * 4 + quad) ^ (l16 & 7)) * 8];
        acc[nt] = MFMA16(af, bfr, acc[nt]);
      }
    }
  }
#pragma unroll
  for (int nt = 0; nt < 4; nt++)
#pragma unroll
    for (int r = 0; r < 4; r++)
      out[((size_t)(b * 512 + q0 + wave * 16 + quad * 4 + r)) * 512 + e0 + nt * 16 + l16] = acc[nt][r];
}

// ---------------------------------------------------------------- launch

extern "C" void kernel_launch(void* const* d_in, const int* in_sizes, int n_in,
                              void* d_out, int out_size, void* d_ws, size_t ws_size,
                              hipStream_t stream) {
  const float* q   = (const float*)d_in[0];
  const int*   att = (const int*)d_in[1];
  const int*   grp = (const int*)d_in[2];
  const int*   sd  = (const int*)d_in[3];
  WPtrs wp;
  for (int j = 0; j < 12; j++) wp.w[j] = (const float*)d_in[4 + j];
  const float* wout = (const float*)d_in[16];

  char* ws = (char*)d_ws;
  // workspace layout (total 126,353,408 B)
  u16* qb    = (u16*)(ws + 0);            //   8,388,608
  u16* Wbt   = (u16*)(ws + 8388608);      //   6,291,456
  u16* Wot   = (u16*)(ws + 14680064);     //     524,288
  u64* RB    = (u64*)(ws + 15204352);     //   2,097,152  (bit-packed masks)
  u16* P     = (u16*)(ws + 17301504);     // 100,663,296
  u16* heads = (u16*)(ws + 117964800);    //   8,388,608
  float* out = (float*)d_out;

  pack_rows_k<<<512, 256, 0, stream>>>(att, grp, sd, RB);
  pack_cols_k<<<128, 256, 0, stream>>>(att, RB);
  prep_q_k<<<2048, 256, 0, stream>>>(q, qb);
  prep_w_k<<<96, 256, 0, stream>>>(wp, Wbt);
  prep_wout_k<<<8, 256, 0, stream>>>(wout, Wot);
  gemm_proj_k<<<dim3(64, 48), 256, 0, stream>>>(qb, Wbt, P);
  attn_k<<<1024, 256, 0, stream>>>(P, RB, heads);
  gemm_out_k<<<dim3(128, 8), 256, 0, stream>>>(heads, Wot, out);
}

// Round 5
// 381.448 us; speedup vs baseline: 1.2594x; 1.0081x over previous
//
#include <hip/hip_runtime.h>

// Problem constants: H=8, B=16, G=512, NQ=512, D=512, KD=VD=64, E=512, NORM=0.125
using u8 = unsigned char;
using u16 = unsigned short;
using u32 = unsigned int;
using u64 = unsigned long long;

typedef __attribute__((ext_vector_type(8))) __bf16 bf16x8;
typedef __attribute__((ext_vector_type(2))) __bf16 bf16x2;
typedef __attribute__((ext_vector_type(8))) u16 u16x8;
typedef __attribute__((ext_vector_type(4))) float f32x4;
typedef __attribute__((ext_vector_type(2))) float f32x2;
typedef __attribute__((ext_vector_type(2))) u32 u32x2;

#define MFMA16(A, B, C) __builtin_amdgcn_mfma_f32_16x16x32_bf16((A), (B), (C), 0, 0, 0)

#if __has_builtin(__builtin_amdgcn_exp2f)
#define EXP2(x) __builtin_amdgcn_exp2f(x)
#else
#define EXP2(x) __expf((x)*0.69314718055994531f)
#endif

__device__ __forceinline__ u16 f2bf(float f) {
  u32 u = __builtin_bit_cast(u32, f);
  u += 0x7fffu + ((u >> 16) & 1u);   // round-to-nearest-even
  return (u16)(u >> 16);
}

// async 16B/lane global->LDS DMA. lds dest must be wave-uniform base; lane i
// lands at base + i*16.
__device__ __forceinline__ void gl_lds16(const void* g, void* l) {
  __builtin_amdgcn_global_load_lds(
      (const __attribute__((address_space(1))) void*)g,
      (__attribute__((address_space(3))) void*)l, 16, 0, 0);
}

// ---------------------------------------------------------------- prep kernels

__global__ void prep_q_k(const float* __restrict__ q, u16* __restrict__ qb) {
  int idx = blockIdx.x * 256 + threadIdx.x;          // one per 8 elems
  const float4* p = (const float4*)q + (size_t)idx * 2;
  float4 a = p[0], b = p[1];
  u32 w0 = f2bf(a.x) | ((u32)f2bf(a.y) << 16);
  u32 w1 = f2bf(a.z) | ((u32)f2bf(a.w) << 16);
  u32 w2 = f2bf(b.x) | ((u32)f2bf(b.y) << 16);
  u32 w3 = f2bf(b.z) | ((u32)f2bf(b.w) << 16);
  ((uint4*)qb)[idx] = make_uint4(w0, w1, w2, w3);
}

struct WPtrs { const float* w[12]; };

// Wbt[col][d] = W_iw[h][d][kk],  col = iw*512 + h*64 + kk  (K-major for B-fragments)
// Q-branch weights (iw%3==0) pre-scaled by 0.125*log2(e) so attn uses bare exp2.
__global__ void prep_w_k(WPtrs wp, u16* __restrict__ Wbt) {
  int iw = blockIdx.x >> 3;
  int h  = blockIdx.x & 7;
  int kk = threadIdx.x & 63;
  int dd = threadIdx.x >> 6;
  float scale = ((iw % 3) == 0) ? 0.18033688011112042f : 1.0f;  // 0.125*log2e
  const float* W = wp.w[iw];
  for (int d = dd; d < 512; d += 4) {
    float v = W[((size_t)(h * 512 + d)) * 64 + kk] * scale;   // coalesced over kk
    Wbt[((size_t)(iw * 512 + h * 64 + kk)) * 512 + d] = f2bf(v);
  }
}

// Wot[h][e][v] = W_out[h][v][e]
__global__ void prep_wout_k(const float* __restrict__ wout, u16* __restrict__ Wot) {
  int h = blockIdx.x;
  int t = threadIdx.x;
  for (int ee = 0; ee < 2; ee++) {
    int e = ee * 256 + t;
    for (int v = 0; v < 64; v++)
      Wot[((size_t)(h * 512 + e)) * 64 + v] = f2bf(wout[((size_t)(h * 64 + v)) * 512 + e]);
  }
}

// ---------------------------------------------------------------- mask bit-pack
// RB[b][c][q][gc] (u64): bit (g&63) of chunk gc = mask_c(b, q, gc*64+g)
//   c0 = sd[b][q][g], c1 = att[b][g][q], c2 = att_flat[b][q][g], c3 = grp[b][q][g]

__global__ void pack_rows_k(const int* __restrict__ att, const int* __restrict__ grp,
                            const int* __restrict__ sd, u64* __restrict__ RB) {
  int t = threadIdx.x, wave = t >> 6, lane = t & 63;
  int b = blockIdx.x >> 5, qc = blockIdx.x & 31;   // 512 blocks
  int q0 = qc * 16 + wave * 4;
#pragma unroll
  for (int r = 0; r < 4; r++) {
    int q = q0 + r;
    size_t rbase = ((size_t)(b * 512 + q)) * 512;
#pragma unroll
    for (int gc = 0; gc < 8; gc++) {
      u64 m0 = __ballot(sd [rbase + gc * 64 + lane] != 0);
      u64 m2 = __ballot(att[rbase + gc * 64 + lane] != 0);
      u64 m3 = __ballot(grp[rbase + gc * 64 + lane] != 0);
      if (lane == 0) {
        size_t ob = ((size_t)(b * 4) * 512 + q) * 8 + gc;
        RB[ob]            = m0;   // c0
        RB[ob + 2 * 4096] = m2;   // c2
        RB[ob + 3 * 4096] = m3;   // c3
      }
    }
  }
}

__global__ void pack_cols_k(const int* __restrict__ att, u64* __restrict__ RB) {
  int t = threadIdx.x, wave = t >> 6, lane = t & 63;
  int b = blockIdx.x >> 3, gc = blockIdx.x & 7;    // 128 blocks
  const int* col = att + ((size_t)(b * 512 + gc * 64 + lane)) * 512;  // att[b][g][.]
#pragma unroll 4
  for (int qi = 0; qi < 128; qi++) {
    int q = wave * 128 + qi;
    u64 m = __ballot(col[q] != 0);
    if (lane == 0) RB[((size_t)(b * 4 + 1) * 512 + q) * 8 + gc] = m;
  }
}

// ---------------------------------------------------------------- pass A: all 12 projections
// C(8192 x 6144) = qb(8192 x 512) * W(512 x 6144). 128x128 tile, BK=64, 4 waves.
// Reg-staged prefetch (round-4-validated on attn): tile k+1's 8 uint4/thread
// loaded to NAMED registers at top of step k (latency hides under ds_read+MFMA),
// ds_write'd to LDS after the reads-done barrier. The old global_load_lds path
// exposed the full L2 round-trip at the vmcnt(0) drain every K-step. LDS layout
// identical (store addr = DMA's lane*16 rule), so fragment reads unchanged.
__global__ __launch_bounds__(256) void gemm_proj_k(const u16* __restrict__ qb,
                                                   const u16* __restrict__ Wbt,
                                                   u16* __restrict__ P) {
  __shared__ __align__(16) u16 smem[17408];  // As 8192 | Bs 8192; Cs overlays 128x136
  u16* As = smem;
  u16* Bs = smem + 8192;
  int t = threadIdx.x;
  int wave = t >> 6, lane = t & 63, quad = lane >> 4, l16 = lane & 15;
  int m0w = (wave >> 1) * 64, n0w = (wave & 1) * 64;
  int bm = blockIdx.x, bn = blockIdx.y;
  f32x4 acc[4][4] = {};
  int lr8 = lane >> 3;                 // 0..7
  int lc8 = (lane & 7) ^ lr8;         // swizzled logical chunk to fetch
  const u16* ag = qb  + ((size_t)(bm * 128 + wave * 32 + lr8)) * 512 + lc8 * 8;
  const u16* bg = Wbt + ((size_t)(bn * 128 + wave * 32 + lr8)) * 512 + lc8 * 8;
  char* AsB = (char*)As;
  char* BsB = (char*)Bs;
  int stO = wave * 4096 + lane * 16;   // byte offset of this thread's 16B slot (j=0)

  uint4 sA0, sA1, sA2, sA3, sB0, sB1, sB2, sB3;
// named-scalar staging; macros = textual inline, nothing address-taken (rule #20)
#define GLD(k0_) {                                          \
    sA0 = *(const uint4*)(ag + 0 * 4096 + (k0_));           \
    sA1 = *(const uint4*)(ag + 1 * 4096 + (k0_));           \
    sA2 = *(const uint4*)(ag + 2 * 4096 + (k0_));           \
    sA3 = *(const uint4*)(ag + 3 * 4096 + (k0_));           \
    sB0 = *(const uint4*)(bg + 0 * 4096 + (k0_));           \
    sB1 = *(const uint4*)(bg + 1 * 4096 + (k0_));           \
    sB2 = *(const uint4*)(bg + 2 * 4096 + (k0_));           \
    sB3 = *(const uint4*)(bg + 3 * 4096 + (k0_)); }
#define GST() {                                             \
    *(uint4*)(AsB + stO)        = sA0;                      \
    *(uint4*)(AsB + stO + 1024) = sA1;                      \
    *(uint4*)(AsB + stO + 2048) = sA2;                      \
    *(uint4*)(AsB + stO + 3072) = sA3;                      \
    *(uint4*)(BsB + stO)        = sB0;                      \
    *(uint4*)(BsB + stO + 1024) = sB1;                      \
    *(uint4*)(BsB + stO + 2048) = sB2;                      \
    *(uint4*)(BsB + stO + 3072) = sB3; }

  // prologue: stage K-step 0
  GLD(0);
  GST();
  __syncthreads();

  for (int ks = 0; ks < 8; ks++) {
    int k0 = ks * 64;
    if (ks < 7) GLD(k0 + 64);          // flies under the compute below
#pragma unroll
    for (int kc = 0; kc < 2; kc++) {
      bf16x8 am[4], bnf[4];
#pragma unroll
      for (int i = 0; i < 4; i++) {
        int ca = ((kc * 4 + quad) ^ (l16 & 7)) * 8;
        am[i]  = *(const bf16x8*)&As[(m0w + i * 16 + l16) * 64 + ca];
        bnf[i] = *(const bf16x8*)&Bs[(n0w + i * 16 + l16) * 64 + ca];
      }
#pragma unroll
      for (int mt = 0; mt < 4; mt++)
#pragma unroll
        for (int nt = 0; nt < 4; nt++)
          acc[mt][nt] = MFMA16(am[mt], bnf[nt], acc[mt][nt]);
    }
    if (ks < 7) {
      __syncthreads();                 // all LDS reads of step ks done
      GST();                           // own loads ~landed (issued ~770cy ago)
      __syncthreads();                 // stores visible
    }
  }
  // ---------------- epilogue: LDS-staged coalesced stores ----------------
  int iw = bn >> 2;                  // both 64-col groups share iw
  bool isV = (iw % 3) == 2;
  int b  = bm >> 2;
  int n0 = (bm & 3) * 128;
  u16 (*Cs)[136] = (u16(*)[136])smem;  // 128 x 136 u16 = 34816 B
  __syncthreads();
#pragma unroll
  for (int mt = 0; mt < 4; mt++)
#pragma unroll
    for (int nt = 0; nt < 4; nt++)
#pragma unroll
      for (int r = 0; r < 4; r++) {
        int rm = m0w + mt * 16 + quad * 4 + r;
        int cn = n0w + nt * 16 + l16;
        u16 v = f2bf(acc[mt][nt][r]);
        if (!isV) Cs[rm][cn] = v;
        else      Cs[cn][rm] = v;
      }
  __syncthreads();
#pragma unroll
  for (int p = 0; p < 8; p++) {
    int idx = p * 256 + t;
    int seg  = idx & 15;
    int crow = idx >> 4;
    uint4 v = *(const uint4*)&Cs[crow][seg * 8];
    if (!isV) {
      int col = seg * 8;
      int cg = col >> 6, k = col & 63;
      int h = (bn * 2 + cg) & 7;
      u16* dst = P + ((size_t)((iw * 8 + h) * 16 + b)) * 32768 + (size_t)(n0 + crow) * 64 + k;
      *(uint4*)dst = v;
    } else {
      int cg = crow >> 6, k = crow & 63;
      int h = (bn * 2 + cg) & 7;
      u16* dst = P + ((size_t)((iw * 8 + h) * 16 + b)) * 32768 + (size_t)k * 512 + n0 + seg * 8;
      *(uint4*)dst = v;
    }
  }
}

// ---------------------------------------------------------------- pass B: fused masked attention
// 1-D grid, 1024 blocks; block 256 = 4 waves, each wave owns 16 q-rows.
// XCD swizzle keeps each (b,h)'s 512KB K/V panel on one XCD's L2.
// T14 reg-staging with NAMED SCALARS ONLY (round 3's lambda+array version put
// the staging tiles in scratch: VGPR=48, WRITE_SIZE 376MB — rule #20). Next
// tile's K/V loaded to named uint4 regs at top of compute (latency hidden under
// MFMA+softmax), ds_write'd after the post-compute barrier. Swapped QK^T
// (mfma(K,Q)): each lane's 16 scores = one q-row, 4 consecutive g per nt;
// masked-exp packs via cvt_pk into b64 writes, mask bits fold into packed
// words. Raw v_exp_f32 (weights pre-scaled by 0.125*log2e).
__global__ __launch_bounds__(256) void attn_k(const u16* __restrict__ P,
                                              const u64* __restrict__ RB,
                                              u16* __restrict__ heads) {
  __shared__ __align__(16) u16 QPs[4096];    // [64][64]: Q at class start, then P scratch
  __shared__ __align__(16) u16 Ks[4096];     // [64][64] chunk-swizzled
  __shared__ __align__(16) u16 Vs[4096];     // [v][g] chunk-swizzled
  __shared__ __align__(16) u64 Ms[64][10];   // row bitmasks, padded (conflict-free b64)
  int t = threadIdx.x;
  int wave = t >> 6, lane = t & 63, quad = lane >> 4, l16 = lane & 15;
  // id = 8*((bh>>3)*8 + qt) + (bh&7)  — bijective; id%8 keyed to bh
  int id = blockIdx.x;
  int r8 = id & 7, kk2 = id >> 3;
  int bh = ((kk2 >> 3) << 3) | r8;
  int qt = kk2 & 7;
  int b = bh & 15, h = bh >> 4;
  int q0 = qt * 64;
  int lr8 = lane >> 3, lc8 = (lane & 7) ^ lr8;
  f32x4 O0 = {}, O1 = {}, O2 = {}, O3 = {};
  f32x4 Oden = {};
  u16x8 ov = {0x3F80, 0x3F80, 0x3F80, 0x3F80, 0x3F80, 0x3F80, 0x3F80, 0x3F80};
  bf16x8 ones = __builtin_bit_cast(bf16x8, ov);   // bf16 1.0 x8

  uint4 rK0, rK1, rV0, rV1, rQ0, rQ1, rM;
  char* KsB = (char*)Ks;
  char* VsB = (char*)Vs;
  char* QsB = (char*)QPs;
  int stOff = (wave * 16 + lr8) * 128 + (lane & 7) * 16;   // +1024 for second 8 rows

// all staging through named scalars; macros = textual inline, nothing address-taken
#define LOADKV(c, g0) {                                                              \
    const u16* PK_ = P + ((size_t)((3 * (c) + 1) * 8 + h) * 16 + b) * 32768;         \
    const u16* PV_ = P + ((size_t)((3 * (c) + 2) * 8 + h) * 16 + b) * 32768;         \
    rK0 = *(const uint4*)(PK_ + (size_t)((g0) + wave * 16 + lr8) * 64 + lc8 * 8);    \
    rK1 = *(const uint4*)(PK_ + (size_t)((g0) + wave * 16 + 8 + lr8) * 64 + lc8 * 8);\
    rV0 = *(const uint4*)(PV_ + (size_t)(wave * 16 + lr8) * 512 + (g0) + lc8 * 8);   \
    rV1 = *(const uint4*)(PV_ + (size_t)(wave * 16 + 8 + lr8) * 512 + (g0) + lc8 * 8);}
#define STOREKV() {                                                                  \
    *(uint4*)(KsB + stOff)        = rK0;                                             \
    *(uint4*)(KsB + stOff + 1024) = rK1;                                             \
    *(uint4*)(VsB + stOff)        = rV0;                                             \
    *(uint4*)(VsB + stOff + 1024) = rV1; }
#define LOADQM(c) {                                                                  \
    const u16* PQ_ = P + ((size_t)((3 * (c)) * 8 + h) * 16 + b) * 32768;             \
    rQ0 = *(const uint4*)(PQ_ + (size_t)(q0 + wave * 16 + lr8) * 64 + lc8 * 8);      \
    rQ1 = *(const uint4*)(PQ_ + (size_t)(q0 + wave * 16 + 8 + lr8) * 64 + lc8 * 8);  \
    rM  = *(const uint4*)(RB + ((size_t)((b * 4 + (c)) * 512 + q0 + (t >> 2))) * 8 + (t & 3) * 2); }
#define STOREQM() {                                                                  \
    *(uint4*)(QsB + stOff)        = rQ0;                                             \
    *(uint4*)(QsB + stOff + 1024) = rQ1;                                             \
    *(uint4*)((char*)Ms + (t >> 2) * 80 + (t & 3) * 16) = rM; }

  // prologue: tile (c=0, gt=0)
  LOADKV(0, 0);
  LOADQM(0);
  STOREKV();
  STOREQM();
  __syncthreads();

  bf16x8 aq0, aq1;
  for (int tt = 0; tt < 32; tt++) {
    int gt = tt & 7;
    if (gt == 0) {                 // Q fragments gt-invariant: hoist (QPs then free for P)
      aq0 = *(const bf16x8*)&QPs[(wave * 16 + l16) * 64 + ((quad) ^ (l16 & 7)) * 8];
      aq1 = *(const bf16x8*)&QPs[(wave * 16 + l16) * 64 + ((4 + quad) ^ (l16 & 7)) * 8];
    }
    int nxt = tt + 1;
    int nc = nxt >> 3, ngt = nxt & 7;
    if (nxt < 32) {
      LOADKV(nc, ngt * 64);        // issue now; lands during compute below
      if (ngt == 0) LOADQM(nc);
    }
    // --- QK^T, swapped operands: D rows = g (A=K), cols = q (B=Q) ---
    f32x4 S0, S1, S2, S3;
#define QKNT(Sn, nt) {                                                                \
      bf16x8 bk0_ = *(const bf16x8*)&Ks[((nt) * 16 + l16) * 64 + ((quad) ^ (l16 & 7)) * 8];     \
      bf16x8 bk1_ = *(const bf16x8*)&Ks[((nt) * 16 + l16) * 64 + ((4 + quad) ^ (l16 & 7)) * 8]; \
      f32x4 sa_ = {};                                                                 \
      sa_ = MFMA16(bk0_, aq0, sa_);                                                   \
      sa_ = MFMA16(bk1_, aq1, sa_);                                                   \
      Sn = sa_; }
    QKNT(S0, 0) QKNT(S1, 1) QKNT(S2, 2) QKNT(S3, 3)
    // S*[r]: q = wave*16+l16, g = gt*64 + nt*16 + quad*4 + r
    // --- masked exp -> packed bf16, b64 writes into Ps (overlays QPs) ---
    {
      u64 m = Ms[wave * 16 + l16][gt];
      u32 mlo = (u32)m, mhi = (u32)(m >> 32);
      int shq = quad * 4;
      u32 tb0 = mlo >> shq, tb1 = mlo >> (shq + 16);
      u32 tb2 = mhi >> shq, tb3 = mhi >> (shq + 16);
      char* PsB = (char*)QPs + (wave * 16 + l16) * 128 + (quad & 1) * 8;
#define PPACK(Sn, tn, nt) {                                                           \
        f32x2 p0_ = {EXP2(Sn[0]), EXP2(Sn[1])};                                       \
        f32x2 p1_ = {EXP2(Sn[2]), EXP2(Sn[3])};                                       \
        u32 w0_ = __builtin_bit_cast(u32, __builtin_convertvector(p0_, bf16x2));      \
        u32 w1_ = __builtin_bit_cast(u32, __builtin_convertvector(p1_, bf16x2));      \
        u32 ma_ = (u32)((int)((tn) << 31) >> 31);                                     \
        u32 mb_ = (u32)((int)((tn) << 30) >> 31);                                     \
        u32 mc_ = (u32)((int)((tn) << 29) >> 31);                                     \
        u32 md_ = (u32)((int)((tn) << 28) >> 31);                                     \
        w0_ &= (ma_ & 0x0000ffffu) | (mb_ & 0xffff0000u);                             \
        w1_ &= (mc_ & 0x0000ffffu) | (md_ & 0xffff0000u);                             \
        u32x2 wp_ = {w0_, w1_};                                                       \
        int ch_ = ((nt) * 2 + (quad >> 1)) ^ (l16 & 7);                               \
        *(u32x2*)(PsB + ch_ * 16) = wp_; }
      PPACK(S0, tb0, 0) PPACK(S1, tb1, 1) PPACK(S2, tb2, 2) PPACK(S3, tb3, 3)
    }
    // --- PV + denominator (P rows are wave-private: no barrier needed) ---
#define PVKC(kc) {                                                                    \
      bf16x8 ap_ = *(const bf16x8*)&QPs[(wave * 16 + l16) * 64 + ((((kc) * 4 + quad) ^ (l16 & 7)) * 8)]; \
      bf16x8 bv0_ = *(const bf16x8*)&Vs[(0 * 16 + l16) * 64 + ((((kc) * 4 + quad) ^ (l16 & 7)) * 8)];    \
      bf16x8 bv1_ = *(const bf16x8*)&Vs[(1 * 16 + l16) * 64 + ((((kc) * 4 + quad) ^ (l16 & 7)) * 8)];    \
      bf16x8 bv2_ = *(const bf16x8*)&Vs[(2 * 16 + l16) * 64 + ((((kc) * 4 + quad) ^ (l16 & 7)) * 8)];    \
      bf16x8 bv3_ = *(const bf16x8*)&Vs[(3 * 16 + l16) * 64 + ((((kc) * 4 + quad) ^ (l16 & 7)) * 8)];    \
      O0 = MFMA16(ap_, bv0_, O0);                                                     \
      O1 = MFMA16(ap_, bv1_, O1);                                                     \
      O2 = MFMA16(ap_, bv2_, O2);                                                     \
      O3 = MFMA16(ap_, bv3_, O3);                                                     \
      Oden = MFMA16(ap_, ones, Oden); }
    PVKC(0) PVKC(1)
    __syncthreads();               // all LDS reads of this gt done
    if (nxt < 32) {
      STOREKV();                   // vmcnt wait lands here: loads flew during compute
      if (ngt == 0) STOREQM();
    }
    __syncthreads();               // stores visible for next gt
  }
#pragma unroll
  for (int r = 0; r < 4; r++) {
    float den = Oden[r];           // every lane holds its rows' denominator
    float i0 = (den > 0.f) ? O0[r] / den : 0.f;
    float i1 = (den > 0.f) ? O1[r] / den : 0.f;
    float i2 = (den > 0.f) ? O2[r] / den : 0.f;
    float i3 = (den > 0.f) ? O3[r] / den : 0.f;
    size_t base = ((size_t)(h * 16 + b) * 512 + q0 + wave * 16 + quad * 4 + r) * 64 + l16;
    heads[base + 0]  = f2bf(i0);
    heads[base + 16] = f2bf(i1);
    heads[base + 32] = f2bf(i2);
    heads[base + 48] = f2bf(i3);
  }
}

// ---------------------------------------------------------------- pass C: out = heads x W_out
// out(8192 x 512) = heads[(b,q),(h,v)=512] * Wot. 64x64 tile, K-loop over h.
__global__ __launch_bounds__(256) void gemm_out_k(const u16* __restrict__ heads,
                                                  const u16* __restrict__ Wot,
                                                  float* __restrict__ out) {
  __shared__ __align__(16) u16 As[4096];
  __shared__ __align__(16) u16 Bs[4096];
  int t = threadIdx.x;
  int wave = t >> 6, lane = t & 63, quad = lane >> 4, l16 = lane & 15;
  int m0 = blockIdx.x * 64, e0 = blockIdx.y * 64;
  int b = m0 >> 9, q0 = m0 & 511;
  int lr8 = lane >> 3, lc8 = (lane & 7) ^ lr8;
  f32x4 acc[4] = {};
  for (int h = 0; h < 8; h++) {
    __syncthreads();
#pragma unroll
    for (int j = 0; j < 2; j++) {
      gl_lds16(heads + ((size_t)(h * 16 + b) * 512 + q0 + wave * 16 + j * 8 + lr8) * 64 + lc8 * 8,
               As + wave * 1024 + j * 512);
      gl_lds16(Wot + ((size_t)(h * 512 + e0 + wave * 16 + j * 8 + lr8)) * 64 + lc8 * 8,
               Bs + wave * 1024 + j * 512);
    }
    __syncthreads();
#pragma unroll
    for (int kc = 0; kc < 2; kc++) {
      bf16x8 af = *(const bf16x8*)&As[(wave * 16 + l16) * 64 + ((kc * 4 + quad) ^ (l16 & 7)) * 8];
#pragma unroll
      for (int nt = 0; nt < 4; nt++) {
        bf16x8 bfr = *(const bf16x8*)&Bs[(nt * 16 + l16) * 64 + ((kc * 4 + quad) ^ (l16 & 7)) * 8];
        acc[nt] = MFMA16(af, bfr, acc[nt]);
      }
    }
  }
#pragma unroll
  for (int nt = 0; nt < 4; nt++)
#pragma unroll
    for (int r = 0; r < 4; r++)
      out[((size_t)(b * 512 + q0 + wave * 16 + quad * 4 + r)) * 512 + e0 + nt * 16 + l16] = acc[nt][r];
}

// ---------------------------------------------------------------- launch

extern "C" void kernel_launch(void* const* d_in, const int* in_sizes, int n_in,
                              void* d_out, int out_size, void* d_ws, size_t ws_size,
                              hipStream_t stream) {
  const float* q   = (const float*)d_in[0];
  const int*   att = (const int*)d_in[1];
  const int*   grp = (const int*)d_in[2];
  const int*   sd  = (const int*)d_in[3];
  WPtrs wp;
  for (int j = 0; j < 12; j++) wp.w[j] = (const float*)d_in[4 + j];
  const float* wout = (const float*)d_in[16];

  char* ws = (char*)d_ws;
  // workspace layout (total 126,353,408 B)
  u16* qb    = (u16*)(ws + 0);            //   8,388,608
  u16* Wbt   = (u16*)(ws + 8388608);      //   6,291,456
  u16* Wot   = (u16*)(ws + 14680064);     //     524,288
  u64* RB    = (u64*)(ws + 15204352);     //   2,097,152  (bit-packed masks)
  u16* P     = (u16*)(ws + 17301504);     // 100,663,296
  u16* heads = (u16*)(ws + 117964800);    //   8,388,608
  float* out = (float*)d_out;

  pack_rows_k<<<512, 256, 0, stream>>>(att, grp, sd, RB);
  pack_cols_k<<<128, 256, 0, stream>>>(att, RB);
  prep_q_k<<<2048, 256, 0, stream>>>(q, qb);
  prep_w_k<<<96, 256, 0, stream>>>(wp, Wbt);
  prep_wout_k<<<8, 256, 0, stream>>>(wout, Wot);
  gemm_proj_k<<<dim3(64, 48), 256, 0, stream>>>(qb, Wbt, P);
  attn_k<<<1024, 256, 0, stream>>>(P, RB, heads);
  gemm_out_k<<<dim3(128, 8), 256, 0, stream>>>(heads, Wot, out);
}